// Round 1
// baseline (57.858 us; speedup 1.0000x reference)
//
#include <hip/hip_runtime.h>
#include <cstdint>

typedef unsigned short ushort_t;
typedef unsigned int uint32;

typedef __bf16 bf16x8 __attribute__((ext_vector_type(8)));
typedef float f32x4 __attribute__((ext_vector_type(4)));

#define N_ROWS 4096
#define D_COLS 512

__device__ __forceinline__ ushort_t f2bf(float f) {
    uint32 u = __float_as_uint(f);
    u += 0x7fffu + ((u >> 16) & 1u);
    return (ushort_t)(u >> 16);
}

// async global->LDS, 16B per lane
#define GLDS(g, l)                                                            \
    __builtin_amdgcn_global_load_lds(                                         \
        (const __attribute__((address_space(1))) void*)(g),                   \
        (__attribute__((address_space(3))) void*)(l), 16, 0, 0)

// ---------------- kernel 1: convert + row norms + partial column sums -------
__global__ __launch_bounds__(256) void k_prep(const float* __restrict__ X,
                                              ushort_t* __restrict__ Xb,
                                              float* __restrict__ sq,
                                              float* __restrict__ partial) {
    __shared__ float cs[4][512];
    const int tid = threadIdx.x;
    const int w = tid >> 6, l = tid & 63;
    const int row0 = blockIdx.x * 64 + w * 16;   // 64 blocks, 16 rows/wave
    float csum[8] = {0.f,0.f,0.f,0.f,0.f,0.f,0.f,0.f};
    for (int r = 0; r < 16; ++r) {
        const int row = row0 + r;
        const float4* src = (const float4*)(X + (size_t)row * D_COLS);
        float4 f0 = src[l * 2];
        float4 f1 = src[l * 2 + 1];
        float v[8] = {f0.x, f0.y, f0.z, f0.w, f1.x, f1.y, f1.z, f1.w};
        float ss = 0.f;
#pragma unroll
        for (int j = 0; j < 8; ++j) { ss += v[j] * v[j]; csum[j] += v[j]; }
        uint4 st;
        st.x = (uint32)f2bf(v[0]) | ((uint32)f2bf(v[1]) << 16);
        st.y = (uint32)f2bf(v[2]) | ((uint32)f2bf(v[3]) << 16);
        st.z = (uint32)f2bf(v[4]) | ((uint32)f2bf(v[5]) << 16);
        st.w = (uint32)f2bf(v[6]) | ((uint32)f2bf(v[7]) << 16);
        *(uint4*)(Xb + (size_t)row * D_COLS + l * 8) = st;
#pragma unroll
        for (int m = 32; m > 0; m >>= 1) ss += __shfl_xor(ss, m, 64);
        if (l == 0) sq[row] = ss;
    }
#pragma unroll
    for (int j = 0; j < 8; ++j) cs[w][l * 8 + j] = csum[j];
    __syncthreads();
    for (int d = tid; d < 512; d += 256)
        partial[blockIdx.x * 512 + d] = cs[0][d] + cs[1][d] + cs[2][d] + cs[3][d];
}

// ---------------- kernel 2: sigma^2 via analytic mean(d2) -------------------
// mean(d2) = (2/N)*sum_i sq_i - (2/N^2)*||colsum||^2
__global__ __launch_bounds__(256) void k_sigma(const float* __restrict__ sq,
                                               const float* __restrict__ partial,
                                               float* __restrict__ cout) {
    __shared__ float red[256];
    const int t = threadIdx.x;
    float s1 = 0.f;
    for (int i = t; i < N_ROWS; i += 256) s1 += sq[i];
    float s2 = 0.f;
    for (int d = t; d < D_COLS; d += 256) {
        float s = 0.f;
        for (int b = 0; b < 64; ++b) s += partial[b * 512 + d];
        s2 += s * s;
    }
    red[t] = s1; __syncthreads();
    for (int st = 128; st > 0; st >>= 1) { if (t < st) red[t] += red[t + st]; __syncthreads(); }
    const float S1 = red[0]; __syncthreads();
    red[t] = s2; __syncthreads();
    for (int st = 128; st > 0; st >>= 1) { if (t < st) red[t] += red[t + st]; __syncthreads(); }
    if (t == 0) {
        const float S2 = red[0];
        const float mean_d2 = 2.f * S1 / (float)N_ROWS
                            - 2.f * S2 / ((float)N_ROWS * (float)N_ROWS);
        const float sigma2 = 1.0f * mean_d2;               // ALPHA = 1.0
        // out = exp(-d2/(2 sigma2)) = exp2(c * d2)
        cout[0] = -1.4426950408889634f / (2.f * sigma2);
    }
}

// ---------------- kernel 3: bf16 MFMA GEMM (X X^T) + fused exp epilogue -----
__global__ __launch_bounds__(256, 2) void k_gemm(const ushort_t* __restrict__ Xb,
                                                 const float* __restrict__ sq,
                                                 const float* __restrict__ cptr,
                                                 float* __restrict__ out) {
    __shared__ ushort_t As[128 * 32];
    __shared__ ushort_t Bs[128 * 32];
    __shared__ float sqA[128], sqB[128];

    const int tid = threadIdx.x;
    const int lane = tid & 63;
    const int w = tid >> 6;
    const int wr = w >> 1, wc = w & 1;          // 2x2 waves -> 64x64 each
    const int i0 = blockIdx.y * 128;
    const int j0 = blockIdx.x * 128;

    const float cval = cptr[0];

    if (tid < 128) sqA[tid] = sq[i0 + tid];
    else           sqB[tid - 128] = sq[j0 + tid - 128];

    // staging: thread tid loads 16B: row tid/4 (+64 for round 1), col (tid&3)*8
    const int srow = tid >> 2;
    const int scol = (tid & 3) * 8;
    const ushort_t* gA = Xb + (size_t)(i0 + srow) * D_COLS + scol;
    const ushort_t* gB = Xb + (size_t)(j0 + srow) * D_COLS + scol;
    ushort_t* lA = As + tid * 8;
    ushort_t* lB = Bs + tid * 8;

    f32x4 acc[4][4];
#pragma unroll
    for (int m = 0; m < 4; ++m)
#pragma unroll
        for (int n = 0; n < 4; ++n) { acc[m][n] = (f32x4){0.f, 0.f, 0.f, 0.f}; }

    const int frow = lane & 15;
    const int fk = (lane >> 4) * 8;

    for (int kt = 0; kt < 16; ++kt) {
        const int k0 = kt * 32;
        GLDS(gA + k0, lA);
        GLDS(gA + 64 * D_COLS + k0, lA + 64 * 32);
        GLDS(gB + k0, lB);
        GLDS(gB + 64 * D_COLS + k0, lB + 64 * 32);
        __syncthreads();

        bf16x8 af[4], bfr[4];
#pragma unroll
        for (int m = 0; m < 4; ++m)
            af[m] = *(const bf16x8*)(As + (wr * 64 + m * 16 + frow) * 32 + fk);
#pragma unroll
        for (int n = 0; n < 4; ++n)
            bfr[n] = *(const bf16x8*)(Bs + (wc * 64 + n * 16 + frow) * 32 + fk);
#pragma unroll
        for (int m = 0; m < 4; ++m)
#pragma unroll
            for (int n = 0; n < 4; ++n)
                acc[m][n] = __builtin_amdgcn_mfma_f32_16x16x32_bf16(
                    af[m], bfr[n], acc[m][n], 0, 0, 0);
        __syncthreads();
    }

    // epilogue: d2 = sqA + sqB - 2*dot ; out = exp2(c * d2)
    const int orow = wr * 64 + (lane >> 4) * 4;
    const int ocol = wc * 64 + (lane & 15);
#pragma unroll
    for (int m = 0; m < 4; ++m) {
#pragma unroll
        for (int n = 0; n < 4; ++n) {
            const int cl = ocol + n * 16;
            const float sqb = sqB[cl];
#pragma unroll
            for (int r = 0; r < 4; ++r) {
                const int rl = orow + m * 16 + r;
                const float d2 = sqA[rl] + sqb - 2.0f * acc[m][n][r];
                out[(size_t)(i0 + rl) * N_ROWS + (j0 + cl)] = exp2f(cval * d2);
            }
        }
    }
}

extern "C" void kernel_launch(void* const* d_in, const int* in_sizes, int n_in,
                              void* d_out, int out_size, void* d_ws, size_t ws_size,
                              hipStream_t stream) {
    const float* X = (const float*)d_in[0];
    float* out = (float*)d_out;
    char* ws = (char*)d_ws;

    ushort_t* Xb     = (ushort_t*)ws;                                  // 4 MB
    float*    sq     = (float*)(ws + (4u << 20));                      // 16 KB
    float*    part   = (float*)(ws + (4u << 20) + (16u << 10));        // 128 KB
    float*    cptr   = (float*)(ws + (4u << 20) + (16u << 10) + (128u << 10));

    hipLaunchKernelGGL(k_prep, dim3(64), dim3(256), 0, stream, X, Xb, sq, part);
    hipLaunchKernelGGL(k_sigma, dim3(1), dim3(256), 0, stream, sq, part, cptr);
    hipLaunchKernelGGL(k_gemm, dim3(32, 32), dim3(256), 0, stream, Xb, sq, cptr, out);
}

// Round 2
// 53.244 us; speedup vs baseline: 1.0867x; 1.0867x over previous
//
#include <hip/hip_runtime.h>
#include <cstdint>

typedef unsigned short u16;
typedef unsigned int u32;
typedef __bf16 bf16x8 __attribute__((ext_vector_type(8)));
typedef float f32x4 __attribute__((ext_vector_type(4)));

#define N_ROWS 4096
#define D_COLS 512

__device__ __forceinline__ u16 f2bf(float f) {
    u32 u = __float_as_uint(f);
    u += 0x7fffu + ((u >> 16) & 1u);
    return (u16)(u >> 16);
}

#define GLDS(g, l)                                                            \
    __builtin_amdgcn_global_load_lds(                                         \
        (const __attribute__((address_space(1))) void*)(g),                   \
        (__attribute__((address_space(3))) void*)(l), 16, 0, 0)

// ---------------- kernel 1: convert + row norms + partial column sums -------
// 256 blocks x 256 threads, 16 rows/block (4 rows/wave)
__global__ __launch_bounds__(256) void k_prep(const float* __restrict__ X,
                                              u16* __restrict__ Xb,
                                              float* __restrict__ sq,
                                              float* __restrict__ partial) {
    __shared__ float cs[4][512];
    const int tid = threadIdx.x;
    const int w = tid >> 6, l = tid & 63;
    const int row0 = blockIdx.x * 16 + w * 4;
    float csum[8] = {0.f,0.f,0.f,0.f,0.f,0.f,0.f,0.f};
#pragma unroll
    for (int r = 0; r < 4; ++r) {
        const int row = row0 + r;
        const float4* src = (const float4*)(X + (size_t)row * D_COLS);
        float4 f0 = src[l * 2];
        float4 f1 = src[l * 2 + 1];
        float v[8] = {f0.x, f0.y, f0.z, f0.w, f1.x, f1.y, f1.z, f1.w};
        float ss = 0.f;
#pragma unroll
        for (int j = 0; j < 8; ++j) { ss += v[j] * v[j]; csum[j] += v[j]; }
        uint4 st;
        st.x = (u32)f2bf(v[0]) | ((u32)f2bf(v[1]) << 16);
        st.y = (u32)f2bf(v[2]) | ((u32)f2bf(v[3]) << 16);
        st.z = (u32)f2bf(v[4]) | ((u32)f2bf(v[5]) << 16);
        st.w = (u32)f2bf(v[6]) | ((u32)f2bf(v[7]) << 16);
        *(uint4*)(Xb + (size_t)row * D_COLS + l * 8) = st;
#pragma unroll
        for (int m = 32; m > 0; m >>= 1) ss += __shfl_xor(ss, m, 64);
        if (l == 0) sq[row] = ss;
    }
#pragma unroll
    for (int j = 0; j < 8; ++j) cs[w][l * 8 + j] = csum[j];
    __syncthreads();
    for (int d = tid; d < 512; d += 256)
        partial[blockIdx.x * 512 + d] = cs[0][d] + cs[1][d] + cs[2][d] + cs[3][d];
}

// ---------------- kernel 2: sigma^2 via analytic mean(d2) -------------------
// mean(d2) = (2/N)*sum_i sq_i - (2/N^2)*||colsum||^2 ; 1 block x 1024 threads
__global__ __launch_bounds__(1024) void k_sigma(const float* __restrict__ sq,
                                                const float* __restrict__ partial,
                                                float* __restrict__ cout) {
    __shared__ float red[1024];
    const int t = threadIdx.x;
    float s1 = sq[t] + sq[t + 1024] + sq[t + 2048] + sq[t + 3072];
    float s2 = 0.f;
    if (t < 512) {
        float s = 0.f;
#pragma unroll 8
        for (int b = 0; b < 256; ++b) s += partial[b * 512 + t];  // coalesced
        s2 = s * s;
    }
    red[t] = s1; __syncthreads();
    for (int st = 512; st > 0; st >>= 1) { if (t < st) red[t] += red[t + st]; __syncthreads(); }
    const float S1 = red[0]; __syncthreads();
    red[t] = s2; __syncthreads();
    for (int st = 512; st > 0; st >>= 1) { if (t < st) red[t] += red[t + st]; __syncthreads(); }
    if (t == 0) {
        const float S2 = red[0];
        const float mean_d2 = 2.f * S1 / (float)N_ROWS
                            - 2.f * S2 / ((float)N_ROWS * (float)N_ROWS);
        const float sigma2 = 1.0f * mean_d2;               // ALPHA = 1.0
        cout[0] = -1.4426950408889634f / (2.f * sigma2);   // out = exp2(c*d2)
    }
}

// ---------------- kernel 3: 256x256 bf16 MFMA GEMM, 2-phase dbuf + swizzle --
// 8 waves (2Mx4N), BK=64, per-wave output 128x64, fused exp epilogue.
__global__ __launch_bounds__(512, 2) void k_gemm(const u16* __restrict__ Xb,
                                                 const float* __restrict__ sq,
                                                 const float* __restrict__ cptr,
                                                 float* __restrict__ out) {
    __shared__ u16 As[2][256 * 64];
    __shared__ u16 Bs[2][256 * 64];
    __shared__ float sqA[256], sqB[256];

    const int tid = threadIdx.x;
    const int lane = tid & 63;
    const int wid = tid >> 6;
    const int wr = wid >> 2, wc = wid & 3;      // 2x4 waves
    const int i0 = blockIdx.y * 256;
    const int j0 = blockIdx.x * 256;
    const float cval = cptr[0];

    if (tid < 256) sqA[tid] = sq[i0 + tid];
    else           sqB[tid - 256] = sq[j0 + tid - 256];

    // ---- staging: 8 GLDS per K-tile (4 for A, 4 for B), 8 KB each ----
    // thread t covers LDS (row = g*64 + t/8, byte = (t&7)*16), linear dest.
    // Source column is pre-swizzled: col ^ ((row&7)<<4)  (T2 both-sides).
    const int srow = tid >> 3;                  // 0..63
    const int scb = (tid & 7) * 16;             // 0..112
    const int ssw = scb ^ ((srow & 7) << 4);
    const char* xb = (const char*)Xb;
    const char* pA = xb + (size_t)(i0 + srow) * 1024 + ssw;
    const char* pB = xb + (size_t)(j0 + srow) * 1024 + ssw;

#define STAGE(buf, kt)                                                        \
    do {                                                                      \
        _Pragma("unroll")                                                     \
        for (int g = 0; g < 4; ++g) {                                         \
            GLDS(pA + (size_t)g * 65536 + (kt) * 128,                         \
                 (char*)As[buf] + g * 8192 + tid * 16);                       \
            GLDS(pB + (size_t)g * 65536 + (kt) * 128,                         \
                 (char*)Bs[buf] + g * 8192 + tid * 16);                       \
        }                                                                     \
    } while (0)

    f32x4 acc[8][4];
#pragma unroll
    for (int m = 0; m < 8; ++m)
#pragma unroll
        for (int n = 0; n < 4; ++n) acc[m][n] = (f32x4){0.f, 0.f, 0.f, 0.f};

    const int frow = lane & 15;
    const int klane = lane >> 4;
    const int swz = (frow & 7) << 4;            // read-side swizzle

    STAGE(0, 0);
    __syncthreads();                             // drains vmcnt before barrier

    int cur = 0;
    for (int kt = 0; kt < 8; ++kt) {
        if (kt < 7) {
            if (cur == 0) STAGE(1, kt + 1); else STAGE(0, kt + 1);
        }
#pragma unroll
        for (int ks = 0; ks < 2; ++ks) {
            bf16x8 a[8], b[4];
            const int kb = (ks * 64 + klane * 16) ^ swz;
#pragma unroll
            for (int m = 0; m < 8; ++m)
                a[m] = *(const bf16x8*)((const char*)As[cur] +
                                        (wr * 128 + m * 16 + frow) * 128 + kb);
#pragma unroll
            for (int n = 0; n < 4; ++n)
                b[n] = *(const bf16x8*)((const char*)Bs[cur] +
                                        (wc * 64 + n * 16 + frow) * 128 + kb);
#pragma unroll
            for (int m = 0; m < 8; ++m)
#pragma unroll
                for (int n = 0; n < 4; ++n)
                    acc[m][n] = __builtin_amdgcn_mfma_f32_16x16x32_bf16(
                        a[m], b[n], acc[m][n], 0, 0, 0);
        }
        __syncthreads();                         // next tile staged + reads done
        cur ^= 1;
    }

    // ---- epilogue: d2 = sqA + sqB - 2*dot ; out = exp2(c*d2) ----
    const int q = lane >> 4;
#pragma unroll
    for (int m = 0; m < 8; ++m) {
#pragma unroll
        for (int n = 0; n < 4; ++n) {
            const int col = wc * 64 + n * 16 + frow;
            const float sb = sqB[col];
#pragma unroll
            for (int r = 0; r < 4; ++r) {
                const int row = wr * 128 + m * 16 + q * 4 + r;
                const float d2 = sqA[row] + sb - 2.0f * acc[m][n][r];
                out[(size_t)(i0 + row) * N_ROWS + (j0 + col)] = exp2f(cval * d2);
            }
        }
    }
#undef STAGE
}

extern "C" void kernel_launch(void* const* d_in, const int* in_sizes, int n_in,
                              void* d_out, int out_size, void* d_ws, size_t ws_size,
                              hipStream_t stream) {
    const float* X = (const float*)d_in[0];
    float* out = (float*)d_out;
    char* ws = (char*)d_ws;

    u16*   Xb   = (u16*)ws;                                   // 4 MB
    float* part = (float*)(ws + (4u << 20));                  // 512 KB
    float* sq   = (float*)(ws + (4u << 20) + (512u << 10));   // 16 KB
    float* cptr = (float*)(ws + (4u << 20) + (512u << 10) + (16u << 10));

    hipLaunchKernelGGL(k_prep, dim3(256), dim3(256), 0, stream, X, Xb, sq, part);
    hipLaunchKernelGGL(k_sigma, dim3(1), dim3(1024), 0, stream, sq, part, cptr);
    hipLaunchKernelGGL(k_gemm, dim3(16, 16), dim3(512), 0, stream, Xb, sq, cptr, out);
}

// Round 3
// 45.829 us; speedup vs baseline: 1.2625x; 1.1618x over previous
//
#include <hip/hip_runtime.h>
#include <cstdint>

typedef unsigned short u16;
typedef unsigned int u32;
typedef __bf16 bf16x8 __attribute__((ext_vector_type(8)));
typedef float f32x4 __attribute__((ext_vector_type(4)));

#define N_ROWS 4096
#define D_COLS 512

__device__ __forceinline__ u16 f2bf(float f) {
    u32 u = __float_as_uint(f);
    u += 0x7fffu + ((u >> 16) & 1u);
    return (u16)(u >> 16);
}

#define GLDS(g, l)                                                            \
    __builtin_amdgcn_global_load_lds(                                         \
        (const __attribute__((address_space(1))) void*)(g),                   \
        (__attribute__((address_space(3))) void*)(l), 16, 0, 0)

// ---------------- kernel 1: convert + row norms + partial column sums -------
// 256 blocks x 256 threads, 16 rows/block (4 rows/wave)
__global__ __launch_bounds__(256) void k_prep(const float* __restrict__ X,
                                              u16* __restrict__ Xb,
                                              float* __restrict__ sq,
                                              float* __restrict__ partial) {
    __shared__ float cs[4][512];
    const int tid = threadIdx.x;
    const int w = tid >> 6, l = tid & 63;
    const int row0 = blockIdx.x * 16 + w * 4;
    float csum[8] = {0.f,0.f,0.f,0.f,0.f,0.f,0.f,0.f};
#pragma unroll
    for (int r = 0; r < 4; ++r) {
        const int row = row0 + r;
        const float4* src = (const float4*)(X + (size_t)row * D_COLS);
        float4 f0 = src[l * 2];
        float4 f1 = src[l * 2 + 1];
        float v[8] = {f0.x, f0.y, f0.z, f0.w, f1.x, f1.y, f1.z, f1.w};
        float ss = 0.f;
#pragma unroll
        for (int j = 0; j < 8; ++j) { ss += v[j] * v[j]; csum[j] += v[j]; }
        uint4 st;
        st.x = (u32)f2bf(v[0]) | ((u32)f2bf(v[1]) << 16);
        st.y = (u32)f2bf(v[2]) | ((u32)f2bf(v[3]) << 16);
        st.z = (u32)f2bf(v[4]) | ((u32)f2bf(v[5]) << 16);
        st.w = (u32)f2bf(v[6]) | ((u32)f2bf(v[7]) << 16);
        *(uint4*)(Xb + (size_t)row * D_COLS + l * 8) = st;
#pragma unroll
        for (int m = 32; m > 0; m >>= 1) ss += __shfl_xor(ss, m, 64);
        if (l == 0) sq[row] = ss;
    }
#pragma unroll
    for (int j = 0; j < 8; ++j) cs[w][l * 8 + j] = csum[j];
    __syncthreads();
    for (int d = tid; d < 512; d += 256)
        partial[blockIdx.x * 512 + d] = cs[0][d] + cs[1][d] + cs[2][d] + cs[3][d];
}

// ---------------- kernel 2: S1/S2 partials, 8 blocks ------------------------
// parts[0..7] = S1 partials (sum of sq), parts[8..15] = S2 partials (||colsum||^2)
__global__ __launch_bounds__(256) void k_sigma(const float* __restrict__ sq,
                                               const float* __restrict__ partial,
                                               float* __restrict__ parts) {
    __shared__ float csm[4][64];
    __shared__ float red[8];
    const int g = blockIdx.x;          // 0..7
    const int t = threadIdx.x;         // 0..255
    const int c = g * 64 + (t & 63);
    const int ch = t >> 6;             // 0..3
    float cssum = 0.f;
#pragma unroll 8
    for (int b = ch * 64; b < ch * 64 + 64; ++b) cssum += partial[b * 512 + c];
    csm[ch][t & 63] = cssum;
    float s1 = sq[g * 512 + t] + sq[g * 512 + 256 + t];
    __syncthreads();
    float s2 = 0.f;
    if (t < 64) {
        float v = csm[0][t] + csm[1][t] + csm[2][t] + csm[3][t];
        s2 = v * v;
    }
#pragma unroll
    for (int m = 32; m > 0; m >>= 1) {
        s1 += __shfl_xor(s1, m, 64);
        s2 += __shfl_xor(s2, m, 64);
    }
    if ((t & 63) == 0) { red[ch] = s1; red[4 + ch] = s2; }
    __syncthreads();
    if (t == 0) {
        parts[g] = red[0] + red[1] + red[2] + red[3];
        parts[8 + g] = red[4];         // only wave 0 had nonzero s2
    }
}

// ---------------- kernel 3: 256x256 GEMM, triple-buffer counted-vmcnt -------
// 8 waves (2Mx4N), BK=32, 16 K-tiles, per-wave output 128x64, fused exp.
__global__ __launch_bounds__(512, 2) void k_gemm(const u16* __restrict__ Xb,
                                                 const float* __restrict__ sq,
                                                 const float* __restrict__ parts,
                                                 float* __restrict__ out) {
    __shared__ __align__(16) u16 As[3][256 * 32];   // 16 KB each
    __shared__ __align__(16) u16 Bs[3][256 * 32];
    __shared__ float sqA[256], sqB[256];
    __shared__ float c_sh;

    const int tid = threadIdx.x;
    const int lane = tid & 63;
    const int wid = tid >> 6;
    const int wr = wid >> 2, wc = wid & 3;          // 2x4 waves

    // T1: XCD-aware swizzle — xcd owns an 8(by) x 4(bx) rectangle of tiles
    const int bid = blockIdx.x;                      // 0..255
    const int xcd = bid & 7, rr = bid >> 3;          // rr: 0..31
    const int by = (xcd >> 2) * 8 + (rr & 7);
    const int bx = (xcd & 3) * 4 + (rr >> 3);
    const int i0 = by * 256, j0 = bx * 256;

    if (tid < 256) sqA[tid] = sq[i0 + tid];
    else           sqB[tid - 256] = sq[j0 + tid - 256];
    if (tid == 0) {
        float S1 = 0.f, S2 = 0.f;
#pragma unroll
        for (int i = 0; i < 8; ++i) { S1 += parts[i]; S2 += parts[8 + i]; }
        const float mean_d2 = 2.f * S1 / (float)N_ROWS
                            - 2.f * S2 / ((float)N_ROWS * (float)N_ROWS);
        c_sh = -1.4426950408889634f / (2.f * mean_d2);   // ALPHA=1
    }

    // staging: per K-tile 4 GLDS/thread; A rows srow, srow+128; 64B/row tiles
    const int srow = tid >> 2;                       // 0..127
    const int sby = (tid & 3) * 16;                  // 16B slot in 64B row
    const int ssw = sby ^ ((srow & 3) << 4);         // T2 pre-swizzled source
    const char* xb = (const char*)Xb;
    const char* gA0 = xb + (size_t)(i0 + srow) * 1024 + ssw;
    const char* gA1 = xb + (size_t)(i0 + srow + 128) * 1024 + ssw;
    const char* gB0 = xb + (size_t)(j0 + srow) * 1024 + ssw;
    const char* gB1 = xb + (size_t)(j0 + srow + 128) * 1024 + ssw;

#define STAGE(buf, kt)                                                        \
    do {                                                                      \
        GLDS(gA0 + (kt) * 64, (char*)As[buf] + tid * 16);                     \
        GLDS(gA1 + (kt) * 64, (char*)As[buf] + 8192 + tid * 16);              \
        GLDS(gB0 + (kt) * 64, (char*)Bs[buf] + tid * 16);                     \
        GLDS(gB1 + (kt) * 64, (char*)Bs[buf] + 8192 + tid * 16);              \
    } while (0)

    f32x4 acc[8][4];
#pragma unroll
    for (int m = 0; m < 8; ++m)
#pragma unroll
        for (int n = 0; n < 4; ++n) acc[m][n] = (f32x4){0.f, 0.f, 0.f, 0.f};

    const int frow = lane & 15;
    const int klane = lane >> 4;
    const int asw = (klane * 16) ^ ((frow & 3) << 4);      // read-side swizzle
    const int abase = (wr * 128 + frow) * 64 + asw;        // + m*1024
    const int bbase = (wc * 64 + frow) * 64 + asw;         // + n*1024

    STAGE(0, 0);
    STAGE(1, 1);

    int cb = 0, nb = 2;
    for (int kt = 0; kt < 16; ++kt) {
        // (A) own tile-kt loads landed (kt+1 stays in flight — never drain)
        if (kt < 15) asm volatile("s_waitcnt vmcnt(4)" ::: "memory");
        else         asm volatile("s_waitcnt vmcnt(0)" ::: "memory");
        // (B) all waves' tile-kt landed; all waves done reading tile kt-1
        asm volatile("s_barrier" ::: "memory");
        // (C) prefetch kt+2 into the buffer tile kt-1 just vacated
        if (kt + 2 < 16) STAGE(nb, kt + 2);
        // (D) compute tile kt
        const char* Ab = (const char*)As[cb];
        const char* Bb = (const char*)Bs[cb];
        bf16x8 a[8], b[4];
#pragma unroll
        for (int m = 0; m < 8; ++m) a[m] = *(const bf16x8*)(Ab + abase + m * 1024);
#pragma unroll
        for (int n = 0; n < 4; ++n) b[n] = *(const bf16x8*)(Bb + bbase + n * 1024);
        __builtin_amdgcn_s_setprio(1);
#pragma unroll
        for (int m = 0; m < 8; ++m)
#pragma unroll
            for (int n = 0; n < 4; ++n)
                acc[m][n] = __builtin_amdgcn_mfma_f32_16x16x32_bf16(
                    a[m], b[n], acc[m][n], 0, 0, 0);
        __builtin_amdgcn_s_setprio(0);
        cb = (cb == 2) ? 0 : cb + 1;
        nb = (nb == 2) ? 0 : nb + 1;
    }
#undef STAGE

    // epilogue: d2 = sqA + sqB - 2*dot ; out = exp2(c*d2)
    const float cval = c_sh;
    const int q = lane >> 4;
#pragma unroll
    for (int m = 0; m < 8; ++m) {
#pragma unroll
        for (int n = 0; n < 4; ++n) {
            const int col = wc * 64 + n * 16 + frow;
            const float sb = sqB[col];
#pragma unroll
            for (int r = 0; r < 4; ++r) {
                const int row = wr * 128 + m * 16 + q * 4 + r;
                const float d2 = sqA[row] + sb - 2.0f * acc[m][n][r];
                out[(size_t)(i0 + row) * N_ROWS + (j0 + col)] = exp2f(cval * d2);
            }
        }
    }
}

extern "C" void kernel_launch(void* const* d_in, const int* in_sizes, int n_in,
                              void* d_out, int out_size, void* d_ws, size_t ws_size,
                              hipStream_t stream) {
    const float* X = (const float*)d_in[0];
    float* out = (float*)d_out;
    char* ws = (char*)d_ws;

    u16*   Xb   = (u16*)ws;                                   // 4 MB
    float* part = (float*)(ws + (4u << 20));                  // 512 KB
    float* sq   = (float*)(ws + (4u << 20) + (512u << 10));   // 16 KB
    float* prt  = (float*)(ws + (4u << 20) + (512u << 10) + (16u << 10));

    hipLaunchKernelGGL(k_prep, dim3(256), dim3(256), 0, stream, X, Xb, sq, part);
    hipLaunchKernelGGL(k_sigma, dim3(8), dim3(256), 0, stream, sq, part, prt);
    hipLaunchKernelGGL(k_gemm, dim3(256), dim3(512), 0, stream, Xb, sq, prt, out);
}